// Round 2
// baseline (50.279 us; speedup 1.0000x reference)
//
#include <hip/hip_runtime.h>
#include <hip/hip_bf16.h>
#include <math.h>

// Problem constants: H=1024, E=48, R=32
#define Hh 1024
#define Ee 48
#define Rr 32
#define NTRIP (Ee*Ee*Rr)   // 73728
#define NROWS 128          // 48 A + 32 R + 48 B rows of T
#define HS 32              // h-split for phase 2
#define HRANGE (Hh/HS)     // 32
#define PITCH 36           // LDS row pitch (floats): 32+4; 36*4=144 B (16B-aligned), 36%32=4 -> conflict-free groups

union F4 { float4 v; float f[4]; };

// ---------------- Kernel 1: partial GEMMs  Ppart[fs][row][h] ----------------
// grid (8 row-tiles, FS f-slices), block 256. Thread owns 4 h-columns (h=4*tid+c).
// emb tile (16 rows x fcount) in LDS, read as wave-broadcast b128 (free).
// W1 read as one coalesced float4 per lane per f, prefetched one step ahead.
__global__ __launch_bounds__(256) void k1_gemm(const float* __restrict__ ent,
                                               const float* __restrict__ rel,
                                               const float* __restrict__ W1,
                                               float* __restrict__ Ppart,
                                               int fcount) {
    extern __shared__ float se[];          // [16][fcount]
    const int rt = blockIdx.x;             // 0..7
    const int fs = blockIdx.y;             // 0..FS-1
    const int row0 = rt * 16;
    const int tid = threadIdx.x;

    const float* emb; int foff;
    if (row0 < 48)      { emb = ent + row0 * Hh;        foff = 0;      }
    else if (row0 < 80) { emb = rel + (row0 - 48) * Hh; foff = Hh;     }
    else                { emb = ent + (row0 - 80) * Hh; foff = 2 * Hh; }

    const int f0 = fs * fcount;
    for (int idx = tid; idx < 16 * fcount; idx += 256) {
        const int r = idx / fcount, f = idx % fcount;
        se[idx] = emb[r * Hh + f0 + f];
        (void)f;
    }
    __syncthreads();

    const float* w1base = W1 + (size_t)(foff + f0) * Hh + 4 * tid;

    float acc[16][4];
#pragma unroll
    for (int r = 0; r < 16; ++r)
#pragma unroll
        for (int c = 0; c < 4; ++c) acc[r][c] = 0.f;

    F4 wcur[4];
#pragma unroll
    for (int c = 0; c < 4; ++c)
        wcur[c].v = *reinterpret_cast<const float4*>(w1base + (size_t)c * Hh);

    for (int f = 0; f < fcount; f += 4) {
        // prefetch next 4 W1 rows (clamped on last iter; values unused then)
        const int fn = (f + 4 < fcount) ? f + 4 : f;
        F4 wnxt[4];
#pragma unroll
        for (int c = 0; c < 4; ++c)
            wnxt[c].v = *reinterpret_cast<const float4*>(w1base + (size_t)(fn + c) * Hh);

#pragma unroll
        for (int r = 0; r < 16; ++r) {
            F4 e4; e4.v = *reinterpret_cast<const float4*>(&se[r * fcount + f]); // broadcast
#pragma unroll
            for (int ff = 0; ff < 4; ++ff) {
                const float ev = e4.f[ff];
#pragma unroll
                for (int c = 0; c < 4; ++c)
                    acc[r][c] = fmaf(ev, wcur[ff].f[c], acc[r][c]);
            }
        }
#pragma unroll
        for (int c = 0; c < 4; ++c) wcur[c] = wnxt[c];
    }

    float* outp = Ppart + ((size_t)fs * NROWS + row0) * Hh + 4 * tid;
#pragma unroll
    for (int r = 0; r < 16; ++r) {
        F4 o;
#pragma unroll
        for (int c = 0; c < 4; ++c) o.f[c] = acc[r][c];
        *reinterpret_cast<float4*>(outp + (size_t)r * Hh) = o.v;
    }
}

// ---------------- Kernel 1b: reduce f-slices, fold b1 into rel rows ----------
__global__ __launch_bounds__(256) void k1b_reduce(const float* __restrict__ Ppart,
                                                  const float* __restrict__ b1,
                                                  float* __restrict__ T, int FS) {
    const int idx = blockIdx.x * 256 + threadIdx.x;   // < 128*1024
    const int r = idx >> 10, h = idx & 1023;
    float s = 0.f;
    for (int fs = 0; fs < FS; ++fs) s += Ppart[(size_t)fs * (NROWS * Hh) + idx];
    if (r >= 48 && r < 80) s += b1[h];
    T[idx] = s;
}

// ---------------- Kernel 2: triplet partial logits ---------------------------
// grid (12 i-tiles, 2 j-tiles, 32 h-slices) = 768 blocks (3/CU), block 256 (4 waves).
// wave = i within tile. lane: jG=lane&7, kG=lane>>3.
// thread: 3 j (jG+8*tj) x 4 k (kG+8*tk) = 12 triplets.
__global__ __launch_bounds__(256) void k2_triplets(const float* __restrict__ T,
                                                   const float* __restrict__ W2,
                                                   float* __restrict__ Lpart) {
    __shared__ float sm[60 * PITCH + HRANGE];  // A(4) R(32) B(24) rows + W2 slice
    const int tid = threadIdx.x;
    const int i0 = blockIdx.x * 4;
    const int j0 = blockIdx.y * 24;
    const int h0 = blockIdx.z * HRANGE;

    for (int idx = tid; idx < 60 * HRANGE; idx += 256) {
        const int rsel = idx >> 5;            // /HRANGE(=32)
        const int h = idx & (HRANGE - 1);
        int g;
        if (rsel < 4)       g = i0 + rsel;             // A rows (subject)
        else if (rsel < 36) g = 48 + (rsel - 4);       // R rows
        else                g = 80 + j0 + (rsel - 36); // B rows (object)
        sm[rsel * PITCH + h] = T[g * Hh + h0 + h];
    }
    if (tid < HRANGE) sm[60 * PITCH + tid] = W2[h0 + tid];
    __syncthreads();

    const int wave = tid >> 6;
    const int lane = tid & 63;
    const int jG = lane & 7;
    const int kG = lane >> 3;

    const float* pa = sm + wave * PITCH;
    const float* pw = sm + 60 * PITCH;

    float acc[3][4];
#pragma unroll
    for (int a = 0; a < 3; ++a)
#pragma unroll
        for (int b = 0; b < 4; ++b) acc[a][b] = 0.f;

#pragma unroll
    for (int h4 = 0; h4 < HRANGE; h4 += 4) {
        F4 av, wv, rv[4], bv[3];
        av.v = *reinterpret_cast<const float4*>(pa + h4);
        wv.v = *reinterpret_cast<const float4*>(pw + h4);
#pragma unroll
        for (int tk = 0; tk < 4; ++tk)
            rv[tk].v = *reinterpret_cast<const float4*>(sm + (4 + kG + 8 * tk) * PITCH + h4);
#pragma unroll
        for (int tj = 0; tj < 3; ++tj)
            bv[tj].v = *reinterpret_cast<const float4*>(sm + (36 + jG + 8 * tj) * PITCH + h4);

#pragma unroll
        for (int c = 0; c < 4; ++c) {
            const float a = av.f[c], w = wv.f[c];
            float p[4];
#pragma unroll
            for (int tk = 0; tk < 4; ++tk) p[tk] = a + rv[tk].f[c];
#pragma unroll
            for (int tj = 0; tj < 3; ++tj) {
                const float bb = bv[tj].f[c];
#pragma unroll
                for (int tk = 0; tk < 4; ++tk) {
                    float v = p[tk] + bb;
                    v = v > 0.f ? v : 0.f;
                    acc[tj][tk] = fmaf(v, w, acc[tj][tk]);
                }
            }
        }
    }

    float* lp = Lpart + (size_t)blockIdx.z * NTRIP;
    const int i_ = i0 + wave;
#pragma unroll
    for (int tj = 0; tj < 3; ++tj) {
        const int j_ = j0 + jG + 8 * tj;
#pragma unroll
        for (int tk = 0; tk < 4; ++tk) {
            const int k_ = kG + 8 * tk;
            lp[(i_ * Ee + j_) * Rr + k_] = acc[tj][tk];
        }
    }
}

// ---------------- Kernel 3: reduce h-slices, sigmoid, mask -------------------
__global__ __launch_bounds__(256) void k3_final(const float* __restrict__ Lpart,
                                                const float* __restrict__ b2,
                                                const int* __restrict__ starts,
                                                const int* __restrict__ maxd,
                                                float* __restrict__ out) {
    const int idx = blockIdx.x * 256 + threadIdx.x;   // < 73728
    float s = b2[0];
#pragma unroll
    for (int z = 0; z < HS; ++z) s += Lpart[(size_t)z * NTRIP + idx];
    const int ij = idx >> 5;          // /32
    const int j = ij % Ee;
    const int i = ij / Ee;
    const float sc = 1.f / (1.f + expf(-s));
    int di = starts[i] - starts[j]; if (di < 0) di = -di;
    const bool m = (i != j) && (di <= maxd[0]);
    out[idx] = m ? sc : 0.f;
}

extern "C" void kernel_launch(void* const* d_in, const int* in_sizes, int n_in,
                              void* d_out, int out_size, void* d_ws, size_t ws_size,
                              hipStream_t stream) {
    const float* ent    = (const float*)d_in[0];
    const float* rel    = (const float*)d_in[1];
    const float* W1     = (const float*)d_in[2];
    const float* b1     = (const float*)d_in[3];
    const float* W2     = (const float*)d_in[4];
    const float* b2     = (const float*)d_in[5];
    const int*   starts = (const int*)d_in[6];
    const int*   maxd   = (const int*)d_in[7];
    float* out = (float*)d_out;
    char* ws = (char*)d_ws;

    const size_t lpartB = (size_t)HS * NTRIP * 4;          // 9.4 MB
    // choose FS (f-split) by workspace (observed ws ~256MB, FS=32 path expected)
    int FS = 32;
    while (FS > 2) {
        const size_t ppartB = (size_t)FS * NROWS * Hh * 4;
        const size_t regionA = (ppartB > lpartB) ? ppartB : lpartB;
        if (regionA + (size_t)NROWS * Hh * 4 <= ws_size) break;
        FS >>= 1;
    }
    const size_t ppartB = (size_t)FS * NROWS * Hh * 4;
    const size_t regionA = (ppartB > lpartB) ? ppartB : lpartB;

    float* Ppart = (float*)ws;               // phase-1 partials
    float* Lpart = (float*)ws;               // phase-2 partials (reuses region A)
    float* T     = (float*)(ws + regionA);   // combined table [128][1024]

    const int fcount = Hh / FS;
    k1_gemm<<<dim3(8, FS), 256, 16 * fcount * 4, stream>>>(ent, rel, W1, Ppart, fcount);
    k1b_reduce<<<(NROWS * Hh) / 256, 256, 0, stream>>>(Ppart, b1, T, FS);
    k2_triplets<<<dim3(12, 2, HS), 256, 0, stream>>>(T, W2, Lpart);
    k3_final<<<NTRIP / 256, 256, 0, stream>>>(Lpart, b2, starts, maxd, out);
}